// Round 4
// baseline (961.657 us; speedup 1.0000x reference)
//
#include <hip/hip_runtime.h>
#include <math.h>

#define NB 8
#define NP 2048
#define TOLF 1e-4f
#define EPSF 1e-12f
#define NCH 32          // target chunks of 64
#define CH 64
#define SPT 4           // src pts per thread (2048 / (2 halves * 256 thr))
#define GRID_ITER 512   // 8 batches * 32 chunks * 2 src-halves

// identical fmaf structure used in NN phase and tail => bit-identical P
__device__ inline float3 xform_pt(const float* __restrict__ T,
                                  float x, float y, float z) {
    float3 r;
    r.x = fmaf(T[0], x, fmaf(T[1], y, fmaf(T[2], z, T[9])));
    r.y = fmaf(T[3], x, fmaf(T[4], y, fmaf(T[5], z, T[10])));
    r.z = fmaf(T[6], x, fmaf(T[7], y, fmaf(T[8], z, T[11])));
    return r;
}

// ---------------- 3x3 Kabsch (double, one-sided Jacobi SVD) ----------------
__device__ void kabsch3x3(const double Spq[9], const double Sp[3], const double Sq[3],
                          double R[9], double t[3]) {
    const double invN = 1.0 / (double)NP;
    double cs[3], ct[3];
#pragma unroll
    for (int i = 0; i < 3; ++i) { cs[i] = Sp[i] * invN; ct[i] = Sq[i] * invN; }
    double H[9];
#pragma unroll
    for (int i = 0; i < 3; ++i)
#pragma unroll
        for (int j = 0; j < 3; ++j)
            H[i * 3 + j] = Spq[i * 3 + j] - (double)NP * cs[i] * ct[j];

    double Bc[3][3], V[3][3];
#pragma unroll
    for (int j = 0; j < 3; ++j)
#pragma unroll
        for (int i = 0; i < 3; ++i) {
            Bc[j][i] = H[i * 3 + j];
            V[j][i]  = (i == j) ? 1.0 : 0.0;
        }
    for (int sweep = 0; sweep < 30; ++sweep) {
        bool rotated = false;
        for (int p = 0; p < 2; ++p)
            for (int q = p + 1; q < 3; ++q) {
                double app = 0, aqq = 0, apq = 0;
#pragma unroll
                for (int i = 0; i < 3; ++i) {
                    app += Bc[p][i] * Bc[p][i];
                    aqq += Bc[q][i] * Bc[q][i];
                    apq += Bc[p][i] * Bc[q][i];
                }
                if (apq * apq > 1e-60 + 1e-28 * app * aqq) {
                    rotated = true;
                    double tau = (aqq - app) / (2.0 * apq);
                    double tt  = (tau >= 0 ? 1.0 : -1.0) / (fabs(tau) + sqrt(1.0 + tau * tau));
                    double c   = 1.0 / sqrt(1.0 + tt * tt);
                    double sn  = c * tt;
#pragma unroll
                    for (int i = 0; i < 3; ++i) {
                        double bp = Bc[p][i], bq = Bc[q][i];
                        Bc[p][i] = c * bp - sn * bq;
                        Bc[q][i] = sn * bp + c * bq;
                        double vp = V[p][i], vq = V[q][i];
                        V[p][i] = c * vp - sn * vq;
                        V[q][i] = sn * vp + c * vq;
                    }
                }
            }
        if (!rotated) break;
    }
    double sv[3], U[3][3];
#pragma unroll
    for (int j = 0; j < 3; ++j) {
        sv[j] = sqrt(Bc[j][0] * Bc[j][0] + Bc[j][1] * Bc[j][1] + Bc[j][2] * Bc[j][2]);
        double inv = sv[j] > 0.0 ? 1.0 / sv[j] : 0.0;
#pragma unroll
        for (int i = 0; i < 3; ++i) U[j][i] = Bc[j][i] * inv;
    }
    double detH = H[0] * (H[4] * H[8] - H[5] * H[7])
                - H[1] * (H[3] * H[8] - H[5] * H[6])
                + H[2] * (H[3] * H[7] - H[4] * H[6]);
    double d = (detH >= 0.0) ? 1.0 : -1.0;
    int o[3] = {0, 1, 2};
    if (sv[o[0]] < sv[o[1]]) { int tmp = o[0]; o[0] = o[1]; o[1] = tmp; }
    if (sv[o[0]] < sv[o[2]]) { int tmp = o[0]; o[0] = o[2]; o[2] = tmp; }
    if (sv[o[1]] < sv[o[2]]) { int tmp = o[1]; o[1] = o[2]; o[2] = tmp; }
    double sg[3] = {1.0, 1.0, d};
#pragma unroll
    for (int i = 0; i < 3; ++i)
#pragma unroll
        for (int j = 0; j < 3; ++j) {
            double acc = 0.0;
#pragma unroll
            for (int k = 0; k < 3; ++k) acc += sg[k] * V[o[k]][i] * U[o[k]][j];
            R[i * 3 + j] = acc;
        }
#pragma unroll
    for (int i = 0; i < 3; ++i)
        t[i] = ct[i] - (R[i * 3 + 0] * cs[0] + R[i * 3 + 1] * cs[1] + R[i * 3 + 2] * cs[2]);
}

// ---------------- init ----------------
__global__ __launch_bounds__(256) void icp_init(unsigned long long* __restrict__ keys,
                                                double* __restrict__ Tc,
                                                float* __restrict__ TcF,
                                                float* __restrict__ err,
                                                int* __restrict__ done,
                                                unsigned int* __restrict__ ticket) {
    int g = blockIdx.x * 256 + threadIdx.x;
    if (g < NB * NP) keys[g] = ~0ULL;
    if (g < NB) {
        double* T = Tc + g * 12;
        float*  F = TcF + g * 12;
#pragma unroll
        for (int k = 0; k < 12; ++k) { T[k] = 0.0; F[k] = 0.0f; }
        T[0] = T[4] = T[8] = 1.0;
        F[0] = F[4] = F[8] = 1.0f;
        err[g] = 0.0f;
    }
    if (g < 10) ticket[g] = 0u;
    if (g == 10) *done = 0;
}

// ---------------- one full ICP iteration (NN + last-block tail) ----------------
// grid: 512 blocks = batch(8) x chunk(32) x srchalf(2), 256 threads.
__global__ __launch_bounds__(256, 2) void icp_iter(
        const float* __restrict__ psrc, const float* __restrict__ ptgt,
        unsigned long long* __restrict__ keys,
        double* __restrict__ Tc, float* __restrict__ TcF,
        float* __restrict__ err, int* __restrict__ done,
        unsigned int* __restrict__ ticket, float* __restrict__ out, int it) {
    if (*done) return;

    __shared__ float4 tg[CH];
    __shared__ double sred[NB][16];
    __shared__ int lastflag;

    const int tid  = threadIdx.x;
    const int blk  = blockIdx.x;
    const int b    = blk >> 6;
    const int ch   = (blk >> 1) & 31;
    const int half = blk & 1;

    // stage 64 targets (x,y,z, 0.5*|t|^2)
    if (tid < CH) {
        const float* tp = ptgt + (b * NP + ch * CH + tid) * 3;
        float tx = tp[0], ty = tp[1], tz = tp[2];
        tg[tid] = make_float4(tx, ty, tz, 0.5f * (tx * tx + ty * ty + tz * tz));
    }
    __syncthreads();

    const float* Tb = TcF + b * 12;
    float sx[SPT], sy[SPT], sz[SPT], sm[SPT];
    int jm[SPT];
#pragma unroll
    for (int k = 0; k < SPT; ++k) {
        int s = k * 512 + half * 256 + tid;
        const float* pp = psrc + (b * NP + s) * 3;
        float3 P = xform_pt(Tb, pp[0], pp[1], pp[2]);
        sx[k] = P.x; sy[k] = P.y; sz[k] = P.z;
        sm[k] = INFINITY; jm[k] = 0;
    }

    const int jbase = ch * CH;
#pragma unroll 4
    for (int j = 0; j < CH; ++j) {
        float4 t = tg[j];          // same-address broadcast, conflict-free
        int jg = jbase + j;
#pragma unroll
        for (int k = 0; k < SPT; ++k) {
            float sc = t.w;
            sc = fmaf(-sx[k], t.x, sc);
            sc = fmaf(-sy[k], t.y, sc);
            sc = fmaf(-sz[k], t.z, sc);
            if (sc < sm[k]) { sm[k] = sc; jm[k] = jg; }
        }
    }

    // exact deterministic merge: monotone-encoded (score, idx), atomicMin
    unsigned long long* kb = keys + b * NP;
#pragma unroll
    for (int k = 0; k < SPT; ++k) {
        unsigned u = __float_as_uint(sm[k]);
        u = (u >> 31) ? ~u : (u ^ 0x80000000u);
        unsigned long long key = ((unsigned long long)u << 32) | (unsigned)jm[k];
        int s = k * 512 + half * 256 + tid;
        atomicMin(kb + s, key);
    }

    __threadfence();
    if (tid == 0) {
        unsigned old = atomicAdd(&ticket[it], 1u);
        lastflag = (old == GRID_ITER - 1) ? 1 : 0;
    }
    __syncthreads();
    if (!lastflag) return;

    // ================= tail: runs on the single last block =================
    __threadfence();
    {
        // thread t: batch tb = t>>5, 64 consecutive pts at (t&31)*64
        int tb = tid >> 5;
        int base = (tid & 31) * 64;
        const float* Ft = TcF + tb * 12;
        const float* sp = psrc + tb * NP * 3;
        const float* tp = ptgt + tb * NP * 3;
        unsigned long long* kk = keys + tb * NP;

        double acc[16];
#pragma unroll
        for (int k = 0; k < 16; ++k) acc[k] = 0.0;

        for (int j = 0; j < 64; ++j) {
            int s = base + j;
            unsigned long long key =
                __hip_atomic_load(kk + s, __ATOMIC_RELAXED, __HIP_MEMORY_SCOPE_AGENT);
            kk[s] = ~0ULL;   // reset for next iteration (visible at kernel end)
            unsigned idx = (unsigned)(key & 0xFFFFFFFFu);
            unsigned u = (unsigned)(key >> 32);
            unsigned bits = (u >> 31) ? (u ^ 0x80000000u) : ~u;
            float sc = __uint_as_float(bits);

            const float* pp = sp + s * 3;
            float3 P = xform_pt(Ft, pp[0], pp[1], pp[2]);   // bit-identical to NN phase
            float a2 = P.x * P.x + P.y * P.y + P.z * P.z;
            float d2 = fmaf(2.0f, sc, a2);
            float dist = sqrtf(fmaxf(d2, EPSF));

            const float* qq = tp + idx * 3;
            float qx = qq[0], qy = qq[1], qz = qq[2];

            acc[0] += (double)dist;
            acc[1] += (double)P.x; acc[2] += (double)P.y; acc[3] += (double)P.z;
            acc[4] += (double)qx;  acc[5] += (double)qy;  acc[6] += (double)qz;
            acc[7]  += (double)P.x * qx; acc[8]  += (double)P.x * qy; acc[9]  += (double)P.x * qz;
            acc[10] += (double)P.y * qx; acc[11] += (double)P.y * qy; acc[12] += (double)P.y * qz;
            acc[13] += (double)P.z * qx; acc[14] += (double)P.z * qy; acc[15] += (double)P.z * qz;
        }

        // reduce 32 lanes per batch (lanes 0-31 / 32-63 of each wave)
#pragma unroll
        for (int k = 0; k < 16; ++k) {
            double x = acc[k];
            x += __shfl_down(x, 16);
            x += __shfl_down(x, 8);
            x += __shfl_down(x, 4);
            x += __shfl_down(x, 2);
            x += __shfl_down(x, 1);
            if ((tid & 31) == 0) sred[tb][k] = x;
        }
    }
    __syncthreads();

    if (tid < 64) {
        double s[16];
        float errnew = 0.0f;
        bool conv = true;
        if (tid < NB) {
#pragma unroll
            for (int k = 0; k < 16; ++k) s[k] = sred[tid][k];
            errnew = (float)(s[0] * (1.0 / (double)NP));
            conv = fabsf(errnew - err[tid]) < TOLF;
        }
        unsigned long long m = __ballot(conv);
        int done_new = ((m & 0xFFull) == 0xFFull) ? 1 : 0;
        if (tid == 0 && done_new) *done = 1;

        if (tid < NB) {
            double* T = Tc + tid * 12;
            double To[12];
#pragma unroll
            for (int k = 0; k < 12; ++k) To[k] = T[k];

            if (!done_new) {
                err[tid] = errnew;
                double R[9], t[3];
                kabsch3x3(&s[7], &s[1], &s[4], R, t);
                double Rn[12];
#pragma unroll
                for (int i = 0; i < 3; ++i) {
#pragma unroll
                    for (int j = 0; j < 3; ++j)
                        Rn[i * 3 + j] = R[i * 3 + 0] * To[0 + j]
                                      + R[i * 3 + 1] * To[3 + j]
                                      + R[i * 3 + 2] * To[6 + j];
                    Rn[9 + i] = R[i * 3 + 0] * To[9] + R[i * 3 + 1] * To[10]
                              + R[i * 3 + 2] * To[11] + t[i];
                }
                float* F = TcF + tid * 12;
#pragma unroll
                for (int k = 0; k < 12; ++k) { T[k] = Rn[k]; F[k] = (float)Rn[k]; To[k] = Rn[k]; }
            }

            // out = current cumulative transform (final Kabsch(psrc, T(psrc)) == T)
            float* o = out + tid * 12;
#pragma unroll
            for (int i = 0; i < 3; ++i) {
#pragma unroll
                for (int j = 0; j < 3; ++j) o[i * 4 + j] = (float)To[i * 3 + j];
                o[i * 4 + 3] = (float)To[9 + i];
            }
        }
    }
}

extern "C" void kernel_launch(void* const* d_in, const int* in_sizes, int n_in,
                              void* d_out, int out_size, void* d_ws, size_t ws_size,
                              hipStream_t stream) {
    const float* psrc = (const float*)d_in[0];
    const float* ptgt = (const float*)d_in[1];
    float* out = (float*)d_out;

    char* ws = (char*)d_ws;
    size_t off = 0;
    unsigned long long* keys = (unsigned long long*)(ws + off); off += (size_t)NB * NP * 8; // 128KB
    double* Tc   = (double*)(ws + off); off += NB * 12 * sizeof(double);
    float*  TcF  = (float*)(ws + off);  off += NB * 12 * sizeof(float);
    float*  err  = (float*)(ws + off);  off += 32;
    int*    done = (int*)(ws + off);    off += 16;
    unsigned int* ticket = (unsigned int*)(ws + off);

    icp_init<<<64, 256, 0, stream>>>(keys, Tc, TcF, err, done, ticket);

    for (int it = 0; it < 10; ++it) {
        icp_iter<<<GRID_ITER, 256, 0, stream>>>(psrc, ptgt, keys, Tc, TcF,
                                                err, done, ticket, out, it);
    }
}

// Round 5
// 400.304 us; speedup vs baseline: 2.4023x; 2.4023x over previous
//
#include <hip/hip_runtime.h>
#include <math.h>

#define NB 8
#define NP 2048
#define GRID_ITER 256   // 8 batches * 32 src-chunks of 64
#define TOLF 1e-4f
#define EPSF 1e-12f

// identical fmaf structure everywhere => bit-identical transformed points
__device__ inline float3 xform_pt(const float* __restrict__ T,
                                  float x, float y, float z) {
    float3 r;
    r.x = fmaf(T[0], x, fmaf(T[1], y, fmaf(T[2], z, T[9])));
    r.y = fmaf(T[3], x, fmaf(T[4], y, fmaf(T[5], z, T[10])));
    r.z = fmaf(T[6], x, fmaf(T[7], y, fmaf(T[8], z, T[11])));
    return r;
}

// ---------------- 3x3 Kabsch (double, one-sided Jacobi SVD) ----------------
__device__ void kabsch3x3(const double Spq[9], const double Sp[3], const double Sq[3],
                          double R[9], double t[3]) {
    const double invN = 1.0 / (double)NP;
    double cs[3], ct[3];
#pragma unroll
    for (int i = 0; i < 3; ++i) { cs[i] = Sp[i] * invN; ct[i] = Sq[i] * invN; }
    double H[9];
#pragma unroll
    for (int i = 0; i < 3; ++i)
#pragma unroll
        for (int j = 0; j < 3; ++j)
            H[i * 3 + j] = Spq[i * 3 + j] - (double)NP * cs[i] * ct[j];

    double Bc[3][3], V[3][3];
#pragma unroll
    for (int j = 0; j < 3; ++j)
#pragma unroll
        for (int i = 0; i < 3; ++i) {
            Bc[j][i] = H[i * 3 + j];
            V[j][i]  = (i == j) ? 1.0 : 0.0;
        }
    for (int sweep = 0; sweep < 30; ++sweep) {
        bool rotated = false;
        for (int p = 0; p < 2; ++p)
            for (int q = p + 1; q < 3; ++q) {
                double app = 0, aqq = 0, apq = 0;
#pragma unroll
                for (int i = 0; i < 3; ++i) {
                    app += Bc[p][i] * Bc[p][i];
                    aqq += Bc[q][i] * Bc[q][i];
                    apq += Bc[p][i] * Bc[q][i];
                }
                if (apq * apq > 1e-60 + 1e-28 * app * aqq) {
                    rotated = true;
                    double tau = (aqq - app) / (2.0 * apq);
                    double tt  = (tau >= 0 ? 1.0 : -1.0) / (fabs(tau) + sqrt(1.0 + tau * tau));
                    double c   = 1.0 / sqrt(1.0 + tt * tt);
                    double sn  = c * tt;
#pragma unroll
                    for (int i = 0; i < 3; ++i) {
                        double bp = Bc[p][i], bq = Bc[q][i];
                        Bc[p][i] = c * bp - sn * bq;
                        Bc[q][i] = sn * bp + c * bq;
                        double vp = V[p][i], vq = V[q][i];
                        V[p][i] = c * vp - sn * vq;
                        V[q][i] = sn * vp + c * vq;
                    }
                }
            }
        if (!rotated) break;
    }
    double sv[3], U[3][3];
#pragma unroll
    for (int j = 0; j < 3; ++j) {
        sv[j] = sqrt(Bc[j][0] * Bc[j][0] + Bc[j][1] * Bc[j][1] + Bc[j][2] * Bc[j][2]);
        double inv = sv[j] > 0.0 ? 1.0 / sv[j] : 0.0;
#pragma unroll
        for (int i = 0; i < 3; ++i) U[j][i] = Bc[j][i] * inv;
    }
    double detH = H[0] * (H[4] * H[8] - H[5] * H[7])
                - H[1] * (H[3] * H[8] - H[5] * H[6])
                + H[2] * (H[3] * H[7] - H[4] * H[6]);
    double d = (detH >= 0.0) ? 1.0 : -1.0;
    int o[3] = {0, 1, 2};
    if (sv[o[0]] < sv[o[1]]) { int tmp = o[0]; o[0] = o[1]; o[1] = tmp; }
    if (sv[o[0]] < sv[o[2]]) { int tmp = o[0]; o[0] = o[2]; o[2] = tmp; }
    if (sv[o[1]] < sv[o[2]]) { int tmp = o[1]; o[1] = o[2]; o[2] = tmp; }
    double sg[3] = {1.0, 1.0, d};
#pragma unroll
    for (int i = 0; i < 3; ++i)
#pragma unroll
        for (int j = 0; j < 3; ++j) {
            double acc = 0.0;
#pragma unroll
            for (int k = 0; k < 3; ++k) acc += sg[k] * V[o[k]][i] * U[o[k]][j];
            R[i * 3 + j] = acc;
        }
#pragma unroll
    for (int i = 0; i < 3; ++i)
        t[i] = ct[i] - (R[i * 3 + 0] * cs[0] + R[i * 3 + 1] * cs[1] + R[i * 3 + 2] * cs[2]);
}

// ---------------- init ----------------
__global__ __launch_bounds__(256) void icp_init(double* __restrict__ Tc,
                                                float* __restrict__ TcF,
                                                float* __restrict__ err,
                                                int* __restrict__ done,
                                                unsigned int* __restrict__ ticket) {
    int g = threadIdx.x;
    if (g < NB) {
        double* T = Tc + g * 12;
        float*  F = TcF + g * 12;
#pragma unroll
        for (int k = 0; k < 12; ++k) { T[k] = 0.0; F[k] = 0.0f; }
        T[0] = T[4] = T[8] = 1.0;
        F[0] = F[4] = F[8] = 1.0f;
        err[g] = 0.0f;
    }
    if (g >= 16 && g < 26) ticket[g - 16] = 0u;
    if (g == 26) *done = 0;
}

// ---------------- one full ICP iteration ----------------
// grid: 256 blocks = batch(8) x src-chunk(32 of 64 pts), 256 threads (4 waves).
// Wave w scans target quarter [w*512,(w+1)*512) as 4 contiguous 128-chains.
__global__ __launch_bounds__(256, 2) void icp_iter(
        const float* __restrict__ psrc, const float* __restrict__ ptgt,
        double* __restrict__ partial,
        double* __restrict__ Tc, float* __restrict__ TcF,
        float* __restrict__ err, int* __restrict__ done,
        unsigned int* __restrict__ ticket, float* __restrict__ out, int it) {
    if (*done) return;

    __shared__ float4 tg[NP];          // 32 KB: (x,y,z, 0.5|t|^2)
    __shared__ float2 comb[4][64];
    __shared__ double sred[NB][16];
    __shared__ int lastflag;

    const int tid = threadIdx.x;
    const int blk = blockIdx.x;
    const int b   = blk >> 5;          // batch
    const int sc  = blk & 31;          // src chunk
    const int w   = tid >> 6;          // wave id = target quarter
    const int l   = tid & 63;          // lane = src point within chunk

    // stage all 2048 targets for this batch
    const float* tb = ptgt + b * NP * 3;
    for (int j = tid; j < NP; j += 256) {
        float tx = tb[3 * j + 0], ty = tb[3 * j + 1], tz = tb[3 * j + 2];
        tg[j] = make_float4(tx, ty, tz, 0.5f * (tx * tx + ty * ty + tz * tz));
    }

    // each lane: its own src point, transformed by current Tcum
    const float* pp = psrc + (b * NP + sc * 64 + l) * 3;
    float3 P = xform_pt(TcF + b * 12, pp[0], pp[1], pp[2]);
    __syncthreads();

    // 4 independent min-chains over contiguous 128-target ranges
    float m0 = INFINITY, m1 = INFINITY, m2 = INFINITY, m3 = INFINITY;
    int j0 = 0, j1 = 0, j2 = 0, j3 = 0;
    const int tbase = w * 512;
#pragma unroll 4
    for (int i = 0; i < 128; ++i) {
        float4 t0 = tg[tbase + i];           // wave-uniform address: broadcast
        float4 t1 = tg[tbase + 128 + i];
        float4 t2 = tg[tbase + 256 + i];
        float4 t3 = tg[tbase + 384 + i];
        float s0 = fmaf(-P.x, t0.x, fmaf(-P.y, t0.y, fmaf(-P.z, t0.z, t0.w)));
        float s1 = fmaf(-P.x, t1.x, fmaf(-P.y, t1.y, fmaf(-P.z, t1.z, t1.w)));
        float s2 = fmaf(-P.x, t2.x, fmaf(-P.y, t2.y, fmaf(-P.z, t2.z, t2.w)));
        float s3 = fmaf(-P.x, t3.x, fmaf(-P.y, t3.y, fmaf(-P.z, t3.z, t3.w)));
        if (s0 < m0) { m0 = s0; j0 = tbase + i; }
        if (s1 < m1) { m1 = s1; j1 = tbase + 128 + i; }
        if (s2 < m2) { m2 = s2; j2 = tbase + 256 + i; }
        if (s3 < m3) { m3 = s3; j3 = tbase + 384 + i; }
    }
    // merge chains ascending (strict < => exact first-min tie-break)
    float best = m0; int bj = j0;
    if (m1 < best) { best = m1; bj = j1; }
    if (m2 < best) { best = m2; bj = j2; }
    if (m3 < best) { best = m3; bj = j3; }
    comb[w][l] = make_float2(best, __int_as_float(bj));
    __syncthreads();

    // wave 0: merge the 4 quarters (ascending w), fp64 contributions, reduce
    if (tid < 64) {
        float fb = INFINITY; int fj = 0;
#pragma unroll
        for (int q = 0; q < 4; ++q) {
            float2 e = comb[q][l];
            if (e.x < fb) { fb = e.x; fj = __float_as_int(e.y); }
        }
        float a2 = P.x * P.x + P.y * P.y + P.z * P.z;
        float d2 = fmaf(2.0f, fb, a2);
        float dist = sqrtf(fmaxf(d2, EPSF));
        float4 Q = tg[fj];

        double v[16];
        v[0] = dist;
        v[1] = P.x; v[2] = P.y; v[3] = P.z;
        v[4] = Q.x; v[5] = Q.y; v[6] = Q.z;
        v[7]  = (double)P.x * Q.x; v[8]  = (double)P.x * Q.y; v[9]  = (double)P.x * Q.z;
        v[10] = (double)P.y * Q.x; v[11] = (double)P.y * Q.y; v[12] = (double)P.y * Q.z;
        v[13] = (double)P.z * Q.x; v[14] = (double)P.z * Q.y; v[15] = (double)P.z * Q.z;
#pragma unroll
        for (int k = 0; k < 16; ++k) {
            double x = v[k];
#pragma unroll
            for (int off = 32; off > 0; off >>= 1) x += __shfl_down(x, off);
            v[k] = x;
        }
        if (l == 0) {
            double* dst = partial + blk * 16;
#pragma unroll
            for (int k = 0; k < 16; ++k) dst[k] = v[k];
        }
    }

    // ---- ticket: last block of this iteration runs the tail ----
    __threadfence();
    __syncthreads();
    if (tid == 0) {
        unsigned old = atomicAdd(&ticket[it], 1u);
        lastflag = (old == GRID_ITER - 1) ? 1 : 0;
    }
    __syncthreads();
    if (!lastflag) return;
    __threadfence();

    // ================= tail (single block) =================
    {
        int tb2 = tid >> 5;          // batch (0..7)
        int c32 = tid & 31;          // which chunk-partial
        double acc[16];
        const double* pp2 = partial + (tb2 * 32 + c32) * 16;
#pragma unroll
        for (int k = 0; k < 16; ++k) acc[k] = pp2[k];
#pragma unroll
        for (int k = 0; k < 16; ++k) {
            double x = acc[k];
            x += __shfl_down(x, 16);
            x += __shfl_down(x, 8);
            x += __shfl_down(x, 4);
            x += __shfl_down(x, 2);
            x += __shfl_down(x, 1);
            if (c32 == 0) sred[tb2][k] = x;
        }
    }
    __syncthreads();

    if (tid < 64) {
        double s[16];
        float errnew = 0.0f;
        bool conv = true;
        if (tid < NB) {
#pragma unroll
            for (int k = 0; k < 16; ++k) s[k] = sred[tid][k];
            errnew = (float)(s[0] * (1.0 / (double)NP));
            conv = fabsf(errnew - err[tid]) < TOLF;
        }
        unsigned long long mm = __ballot(conv);
        int done_new = ((mm & 0xFFull) == 0xFFull) ? 1 : 0;
        if (tid == 0 && done_new) *done = 1;

        if (tid < NB) {
            double* T = Tc + tid * 12;
            double To[12];
#pragma unroll
            for (int k = 0; k < 12; ++k) To[k] = T[k];

            if (!done_new) {
                err[tid] = errnew;
                double R[9], t[3];
                kabsch3x3(&s[7], &s[1], &s[4], R, t);
                double Rn[12];
#pragma unroll
                for (int i = 0; i < 3; ++i) {
#pragma unroll
                    for (int j = 0; j < 3; ++j)
                        Rn[i * 3 + j] = R[i * 3 + 0] * To[0 + j]
                                      + R[i * 3 + 1] * To[3 + j]
                                      + R[i * 3 + 2] * To[6 + j];
                    Rn[9 + i] = R[i * 3 + 0] * To[9] + R[i * 3 + 1] * To[10]
                              + R[i * 3 + 2] * To[11] + t[i];
                }
                float* F = TcF + tid * 12;
#pragma unroll
                for (int k = 0; k < 12; ++k) { T[k] = Rn[k]; F[k] = (float)Rn[k]; To[k] = Rn[k]; }
            }

            // out = current cumulative transform (Kabsch(psrc, T(psrc)) == T)
            float* o = out + tid * 12;
#pragma unroll
            for (int i = 0; i < 3; ++i) {
#pragma unroll
                for (int j = 0; j < 3; ++j) o[i * 4 + j] = (float)To[i * 3 + j];
                o[i * 4 + 3] = (float)To[9 + i];
            }
        }
    }
}

extern "C" void kernel_launch(void* const* d_in, const int* in_sizes, int n_in,
                              void* d_out, int out_size, void* d_ws, size_t ws_size,
                              hipStream_t stream) {
    const float* psrc = (const float*)d_in[0];
    const float* ptgt = (const float*)d_in[1];
    float* out = (float*)d_out;

    char* ws = (char*)d_ws;
    size_t off = 0;
    double* partial = (double*)(ws + off); off += (size_t)GRID_ITER * 16 * sizeof(double); // 32KB
    double* Tc   = (double*)(ws + off); off += NB * 12 * sizeof(double);
    float*  TcF  = (float*)(ws + off);  off += NB * 12 * sizeof(float);
    float*  err  = (float*)(ws + off);  off += 32;
    int*    done = (int*)(ws + off);    off += 16;
    unsigned int* ticket = (unsigned int*)(ws + off);

    icp_init<<<1, 256, 0, stream>>>(Tc, TcF, err, done, ticket);

    for (int it = 0; it < 10; ++it) {
        icp_iter<<<GRID_ITER, 256, 0, stream>>>(psrc, ptgt, partial, Tc, TcF,
                                                err, done, ticket, out, it);
    }
}

// Round 6
// 363.469 us; speedup vs baseline: 2.6458x; 1.1013x over previous
//
#include <hip/hip_runtime.h>
#include <math.h>

#define NB 8
#define NP 2048
#define GRID_ITER 256   // 8 batches * 32 src-chunks of 64
#define TOLF 1e-4f
#define EPSF 1e-12f

// identical fmaf structure everywhere => bit-identical transformed points
__device__ inline float3 xform_pt(const float* __restrict__ T,
                                  float x, float y, float z) {
    float3 r;
    r.x = fmaf(T[0], x, fmaf(T[1], y, fmaf(T[2], z, T[9])));
    r.y = fmaf(T[3], x, fmaf(T[4], y, fmaf(T[5], z, T[10])));
    r.z = fmaf(T[6], x, fmaf(T[7], y, fmaf(T[8], z, T[11])));
    return r;
}

// ---------------- 3x3 Kabsch (double, one-sided Jacobi SVD) ----------------
__device__ void kabsch3x3(const double Spq[9], const double Sp[3], const double Sq[3],
                          double R[9], double t[3]) {
    const double invN = 1.0 / (double)NP;
    double cs[3], ct[3];
#pragma unroll
    for (int i = 0; i < 3; ++i) { cs[i] = Sp[i] * invN; ct[i] = Sq[i] * invN; }
    double H[9];
#pragma unroll
    for (int i = 0; i < 3; ++i)
#pragma unroll
        for (int j = 0; j < 3; ++j)
            H[i * 3 + j] = Spq[i * 3 + j] - (double)NP * cs[i] * ct[j];

    double Bc[3][3], V[3][3];
#pragma unroll
    for (int j = 0; j < 3; ++j)
#pragma unroll
        for (int i = 0; i < 3; ++i) {
            Bc[j][i] = H[i * 3 + j];
            V[j][i]  = (i == j) ? 1.0 : 0.0;
        }
    for (int sweep = 0; sweep < 30; ++sweep) {
        bool rotated = false;
        for (int p = 0; p < 2; ++p)
            for (int q = p + 1; q < 3; ++q) {
                double app = 0, aqq = 0, apq = 0;
#pragma unroll
                for (int i = 0; i < 3; ++i) {
                    app += Bc[p][i] * Bc[p][i];
                    aqq += Bc[q][i] * Bc[q][i];
                    apq += Bc[p][i] * Bc[q][i];
                }
                if (apq * apq > 1e-60 + 1e-28 * app * aqq) {
                    rotated = true;
                    double tau = (aqq - app) / (2.0 * apq);
                    double tt  = (tau >= 0 ? 1.0 : -1.0) / (fabs(tau) + sqrt(1.0 + tau * tau));
                    double c   = 1.0 / sqrt(1.0 + tt * tt);
                    double sn  = c * tt;
#pragma unroll
                    for (int i = 0; i < 3; ++i) {
                        double bp = Bc[p][i], bq = Bc[q][i];
                        Bc[p][i] = c * bp - sn * bq;
                        Bc[q][i] = sn * bp + c * bq;
                        double vp = V[p][i], vq = V[q][i];
                        V[p][i] = c * vp - sn * vq;
                        V[q][i] = sn * vp + c * vq;
                    }
                }
            }
        if (!rotated) break;
    }
    double sv[3], U[3][3];
#pragma unroll
    for (int j = 0; j < 3; ++j) {
        sv[j] = sqrt(Bc[j][0] * Bc[j][0] + Bc[j][1] * Bc[j][1] + Bc[j][2] * Bc[j][2]);
        double inv = sv[j] > 0.0 ? 1.0 / sv[j] : 0.0;
#pragma unroll
        for (int i = 0; i < 3; ++i) U[j][i] = Bc[j][i] * inv;
    }
    double detH = H[0] * (H[4] * H[8] - H[5] * H[7])
                - H[1] * (H[3] * H[8] - H[5] * H[6])
                + H[2] * (H[3] * H[7] - H[4] * H[6]);
    double d = (detH >= 0.0) ? 1.0 : -1.0;
    int o[3] = {0, 1, 2};
    if (sv[o[0]] < sv[o[1]]) { int tmp = o[0]; o[0] = o[1]; o[1] = tmp; }
    if (sv[o[0]] < sv[o[2]]) { int tmp = o[0]; o[0] = o[2]; o[2] = tmp; }
    if (sv[o[1]] < sv[o[2]]) { int tmp = o[1]; o[1] = o[2]; o[2] = tmp; }
    double sg[3] = {1.0, 1.0, d};
#pragma unroll
    for (int i = 0; i < 3; ++i)
#pragma unroll
        for (int j = 0; j < 3; ++j) {
            double acc = 0.0;
#pragma unroll
            for (int k = 0; k < 3; ++k) acc += sg[k] * V[o[k]][i] * U[o[k]][j];
            R[i * 3 + j] = acc;
        }
#pragma unroll
    for (int i = 0; i < 3; ++i)
        t[i] = ct[i] - (R[i * 3 + 0] * cs[0] + R[i * 3 + 1] * cs[1] + R[i * 3 + 2] * cs[2]);
}

// ---------------- init ----------------
__global__ __launch_bounds__(256) void icp_init(double* __restrict__ Tc,
                                                float* __restrict__ TcF,
                                                float* __restrict__ err,
                                                int* __restrict__ done,
                                                unsigned int* __restrict__ ticket) {
    int g = threadIdx.x;
    if (g < NB) {
        double* T = Tc + g * 12;
        float*  F = TcF + g * 12;
#pragma unroll
        for (int k = 0; k < 12; ++k) { T[k] = 0.0; F[k] = 0.0f; }
        T[0] = T[4] = T[8] = 1.0;
        F[0] = F[4] = F[8] = 1.0f;
        err[g] = 0.0f;
    }
    if (g >= 16 && g < 26) ticket[g - 16] = 0u;
    if (g == 26) *done = 0;
}

// ---------------- one full ICP iteration ----------------
// grid: 256 blocks = batch(8) x src-chunk(32 of 64 pts), 256 threads.
// thread = (src-group g = tid>>5: 8 pts, target-slice = tid&31: 64 targets).
// Each LDS target read feeds 8 src points (~48 VALU / ds_read_b128).
__global__ __launch_bounds__(256, 2) void icp_iter(
        const float* __restrict__ psrc, const float* __restrict__ ptgt,
        double* __restrict__ partial,
        double* __restrict__ Tc, float* __restrict__ TcF,
        float* __restrict__ err, int* __restrict__ done,
        unsigned int* __restrict__ ticket, float* __restrict__ out, int it) {
    if (*done) return;

    __shared__ float4 tg[2080];        // padded: idx = j + (j>>6); slice stride 65
    __shared__ float4 ps[64];          // transformed src pts (x,y,z,|P|^2)
    __shared__ float2 comb[32][66];    // [slice][src] winners, padded rows
    __shared__ double sred[NB][16];
    __shared__ int lastflag;

    const int tid   = threadIdx.x;
    const int blk   = blockIdx.x;
    const int b     = blk >> 5;        // batch
    const int sc    = blk & 31;        // src chunk
    const int slice = tid & 31;        // target slice (64 targets)
    const int g     = tid >> 5;        // src group (8 pts)

    // stage all 2048 targets for this batch (padded layout)
    const float* tb = ptgt + b * NP * 3;
    for (int j = tid; j < NP; j += 256) {
        float tx = tb[3 * j + 0], ty = tb[3 * j + 1], tz = tb[3 * j + 2];
        tg[j + (j >> 6)] = make_float4(tx, ty, tz,
                                       0.5f * (tx * tx + ty * ty + tz * tz));
    }
    // stage this chunk's 64 src points, transformed once (bit-identical reuse)
    if (tid < 64) {
        const float* pp = psrc + (b * NP + sc * 64 + tid) * 3;
        float3 P = xform_pt(TcF + b * 12, pp[0], pp[1], pp[2]);
        ps[tid] = make_float4(P.x, P.y, P.z, P.x * P.x + P.y * P.y + P.z * P.z);
    }
    __syncthreads();

    // 8 src pts in registers; scan 64 targets of this slice
    float sx[8], sy[8], sz[8], sm[8];
    int jm[8];
#pragma unroll
    for (int k = 0; k < 8; ++k) {
        float4 P = ps[g * 8 + k];
        sx[k] = P.x; sy[k] = P.y; sz[k] = P.z;
        sm[k] = INFINITY; jm[k] = 0;
    }
    const int base = slice * 65, jbase = slice * 64;
#pragma unroll 4
    for (int i = 0; i < 64; ++i) {
        float4 t = tg[base + i];
        int j = jbase + i;
#pragma unroll
        for (int k = 0; k < 8; ++k) {
            float s = fmaf(-sx[k], t.x, fmaf(-sy[k], t.y, fmaf(-sz[k], t.z, t.w)));
            if (s < sm[k]) { sm[k] = s; jm[k] = j; }   // ascending j: first-min
        }
    }
#pragma unroll
    for (int k = 0; k < 8; ++k)
        comb[slice][g * 8 + k] = make_float2(sm[k], __int_as_float(jm[k]));
    __syncthreads();

    // wave 0: merge 32 slices (ascending => exact tie-break), fp64 contributions
    if (tid < 64) {
        float fb = INFINITY; int fj = 0;
#pragma unroll 8
        for (int q = 0; q < 32; ++q) {
            float2 e = comb[q][tid];
            if (e.x < fb) { fb = e.x; fj = __float_as_int(e.y); }
        }
        float4 P = ps[tid];
        float d2 = fmaf(2.0f, fb, P.w);
        float dist = sqrtf(fmaxf(d2, EPSF));
        float4 Q = tg[fj + (fj >> 6)];

        double v[16];
        v[0] = dist;
        v[1] = P.x; v[2] = P.y; v[3] = P.z;
        v[4] = Q.x; v[5] = Q.y; v[6] = Q.z;
        v[7]  = (double)P.x * Q.x; v[8]  = (double)P.x * Q.y; v[9]  = (double)P.x * Q.z;
        v[10] = (double)P.y * Q.x; v[11] = (double)P.y * Q.y; v[12] = (double)P.y * Q.z;
        v[13] = (double)P.z * Q.x; v[14] = (double)P.z * Q.y; v[15] = (double)P.z * Q.z;
#pragma unroll
        for (int k = 0; k < 16; ++k) {
            double x = v[k];
#pragma unroll
            for (int off = 32; off > 0; off >>= 1) x += __shfl_down(x, off);
            v[k] = x;
        }
        if (tid == 0) {
            double* dst = partial + blk * 16;
#pragma unroll
            for (int k = 0; k < 16; ++k) dst[k] = v[k];
        }
    }

    // ---- ticket: last block of this iteration runs the tail ----
    __threadfence();
    __syncthreads();
    if (tid == 0) {
        unsigned old = atomicAdd(&ticket[it], 1u);
        lastflag = (old == GRID_ITER - 1) ? 1 : 0;
    }
    __syncthreads();
    if (!lastflag) return;
    __threadfence();

    // ================= tail (single block) =================
    {
        int tb2 = tid >> 5;          // batch (0..7)
        int c32 = tid & 31;          // which chunk-partial
        double acc[16];
        const double* pp2 = partial + (tb2 * 32 + c32) * 16;
#pragma unroll
        for (int k = 0; k < 16; ++k)
            acc[k] = __hip_atomic_load(pp2 + k, __ATOMIC_RELAXED,
                                       __HIP_MEMORY_SCOPE_AGENT);
#pragma unroll
        for (int k = 0; k < 16; ++k) {
            double x = acc[k];
            x += __shfl_down(x, 16);
            x += __shfl_down(x, 8);
            x += __shfl_down(x, 4);
            x += __shfl_down(x, 2);
            x += __shfl_down(x, 1);
            if (c32 == 0) sred[tb2][k] = x;
        }
    }
    __syncthreads();

    if (tid < 64) {
        double s[16];
        float errnew = 0.0f;
        bool conv = true;
        if (tid < NB) {
#pragma unroll
            for (int k = 0; k < 16; ++k) s[k] = sred[tid][k];
            errnew = (float)(s[0] * (1.0 / (double)NP));
            conv = fabsf(errnew - err[tid]) < TOLF;
        }
        unsigned long long mm = __ballot(conv);
        int done_new = ((mm & 0xFFull) == 0xFFull) ? 1 : 0;
        if (tid == 0 && done_new) *done = 1;

        if (tid < NB) {
            double* T = Tc + tid * 12;
            double To[12];
#pragma unroll
            for (int k = 0; k < 12; ++k) To[k] = T[k];

            if (!done_new) {
                err[tid] = errnew;
                double R[9], t[3];
                kabsch3x3(&s[7], &s[1], &s[4], R, t);
                double Rn[12];
#pragma unroll
                for (int i = 0; i < 3; ++i) {
#pragma unroll
                    for (int j = 0; j < 3; ++j)
                        Rn[i * 3 + j] = R[i * 3 + 0] * To[0 + j]
                                      + R[i * 3 + 1] * To[3 + j]
                                      + R[i * 3 + 2] * To[6 + j];
                    Rn[9 + i] = R[i * 3 + 0] * To[9] + R[i * 3 + 1] * To[10]
                              + R[i * 3 + 2] * To[11] + t[i];
                }
                float* F = TcF + tid * 12;
#pragma unroll
                for (int k = 0; k < 12; ++k) { T[k] = Rn[k]; F[k] = (float)Rn[k]; To[k] = Rn[k]; }
            }

            // out = current cumulative transform (Kabsch(psrc, T(psrc)) == T)
            float* o = out + tid * 12;
#pragma unroll
            for (int i = 0; i < 3; ++i) {
#pragma unroll
                for (int j = 0; j < 3; ++j) o[i * 4 + j] = (float)To[i * 3 + j];
                o[i * 4 + 3] = (float)To[9 + i];
            }
        }
    }
}

extern "C" void kernel_launch(void* const* d_in, const int* in_sizes, int n_in,
                              void* d_out, int out_size, void* d_ws, size_t ws_size,
                              hipStream_t stream) {
    const float* psrc = (const float*)d_in[0];
    const float* ptgt = (const float*)d_in[1];
    float* out = (float*)d_out;

    char* ws = (char*)d_ws;
    size_t off = 0;
    double* partial = (double*)(ws + off); off += (size_t)GRID_ITER * 16 * sizeof(double); // 32KB
    double* Tc   = (double*)(ws + off); off += NB * 12 * sizeof(double);
    float*  TcF  = (float*)(ws + off);  off += NB * 12 * sizeof(float);
    float*  err  = (float*)(ws + off);  off += 32;
    int*    done = (int*)(ws + off);    off += 16;
    unsigned int* ticket = (unsigned int*)(ws + off);

    icp_init<<<1, 256, 0, stream>>>(Tc, TcF, err, done, ticket);

    for (int it = 0; it < 10; ++it) {
        icp_iter<<<GRID_ITER, 256, 0, stream>>>(psrc, ptgt, partial, Tc, TcF,
                                                err, done, ticket, out, it);
    }
}